// Round 8
// baseline (191.264 us; speedup 1.0000x reference)
//
#include <hip/hip_runtime.h>

#define BB 16384
#define DD 256
#define EE 8
#define HH 128
#define TBLK 96           // transpose blocks
#define RPB 64            // rows per dense block
#define CS_S 136          // 128 + 8 bf16 pad

typedef __attribute__((ext_vector_type(8))) short short8;   // 8 bf16 = 4 VGPRs
typedef __attribute__((ext_vector_type(4))) float f32x4;

// fp32 -> bf16 round-to-nearest-even (values are finite; no NaN care needed)
__device__ __forceinline__ ushort f2bf(float f){
    const unsigned u = __float_as_uint(f);
    return (ushort)((u + 0x7fffu + ((u >> 16) & 1u)) >> 16);
}
__device__ __forceinline__ float bf2f(ushort s){
    return __uint_as_float(((unsigned)s) << 16);
}
__device__ __forceinline__ float fast_tanh(float v){
    v = fminf(fmaxf(v, -15.0f), 15.0f);
    const float a = __expf(2.0f * v);
    return (a - 1.0f) / (a + 1.0f);
}

// ---------------------------------------------------------------------------
// Prep (transpose-only): W1 [e][k=256][h=128] fp32 -> W1t [e][h][k] bf16;
// Wp likewise. 96 blocks of 64x64 tiles. Unchanged (verified).
__global__ __launch_bounds__(256) void prep_kernel(
    const float* __restrict__ W1, const float* __restrict__ Wp,
    ushort* __restrict__ W1t, ushort* __restrict__ Wpt)
{
    __shared__ float tile[64 * 68];   // 64x64 fp32 tile, pad 68 vs bank conflicts
    int b = blockIdx.x;
    const int t = threadIdx.x;
    const float* src; ushort* dst; int K;
    int k0, h0;
    if (b < 64){                                    // W1: 8e x 4kt x 2ht
        const int e = b >> 3, kt = (b >> 1) & 3, ht = b & 1;
        src = W1 + (size_t)e * DD * HH;  dst = W1t + (size_t)e * HH * DD;
        K = DD; k0 = kt * 64; h0 = ht * 64;
    } else {                                        // Wp: 8e x 2kt x 2ht
        b -= 64;
        const int e = b >> 2, kt = (b >> 1) & 1, ht = b & 1;
        src = Wp + (size_t)e * HH * HH;  dst = Wpt + (size_t)e * HH * HH;
        K = HH; k0 = kt * 64; h0 = ht * 64;
    }
    #pragma unroll
    for (int j = 0; j < 4; j++){
        const int idx = t + 256 * j;               // 1024 float4 = 64x64
        const int kk = idx >> 4, hh = (idx & 15) * 4;
        const float4 v = *(const float4*)(src + (size_t)(k0 + kk) * HH + h0 + hh);
        *(float4*)&tile[kk * 68 + hh] = v;
    }
    __syncthreads();
    #pragma unroll
    for (int j = 0; j < 4; j++){
        const int idx = t + 256 * j;
        const int hh = idx >> 4, kk = (idx & 15) * 4;
        ushort4 o;
        o.x = f2bf(tile[(kk + 0) * 68 + hh]);
        o.y = f2bf(tile[(kk + 1) * 68 + hh]);
        o.z = f2bf(tile[(kk + 2) * 68 + hh]);
        o.w = f2bf(tile[(kk + 3) * 68 + hh]);
        *(ushort4*)&dst[(size_t)(h0 + hh) * K + k0 + kk] = o;
    }
}

// ---------------------------------------------------------------------------
// Dense kernel v4: 256 blocks x 1024 threads (16 waves), 64 rows/block.
//
// Round-7 diagnosis: 2 MB/block of expert-loop A-fragment LDS re-reads
// (~10 us/CU serial LDS time) + only 2 waves/SIMD. Fixes here:
//   (a) A fragments held in REGISTERS across all 8 experts (X is
//       expert-invariant; 16 rows/wave -> af[8] = 32 VGPRs), loaded
//       directly from global fp32 x with the same RNE f2bf -> values
//       bit-identical to the previous LDS-staged path. Zero LDS traffic
//       in GEMM1.
//   (b) 16 waves = 4 row-groups x 4 col-quarters -> 4 waves/SIMD.
//       Col-quarter B-slices (16 KB/expert) are read by the 4 rg-waves
//       nearly simultaneously -> L1-absorbed; block-level weight traffic
//       stays 768 KB (192 MB total, L2-resident).
//   (c) No launch-bounds register cap beyond the implied 128 (1024-thr
//       block): rounds 3/6 proved aggressive caps -> VGPR=40 + spill.
//
// Wave (rg = wid>>2, cq = wid&3): rows rg*16 + m16, cols cq*32 (2 col-tiles).
// Per expert e: wES <- per-row weight; GEMM1 (A regs, B global) -> relu ->
// coreS; barrier; GEMM2 (A from coreS, B global) -> tanh-mix epilogue ->
// red; barrier. Final: shfl-reduce over m16, redS[4][64] cross-cq sum, store.
// Routing math is BIT-IDENTICAL to the verified kernel (fp32 dots, same
// shfl tree, same top-2 + 2-way softmax) -> identical expert picks.
// bo[e] added on exactly one lane per row (cq==0 && m16==0).
__global__ __launch_bounds__(1024, 1) void dense_kernel(
    const float* __restrict__ x, const float* __restrict__ Wg,
    const ushort* __restrict__ W1t, const float* __restrict__ b1,
    const ushort* __restrict__ Wpt, const float* __restrict__ bp,
    const float* __restrict__ mix_logit, const float* __restrict__ Wo,
    const float* __restrict__ bo, float* __restrict__ out)
{
    __shared__ __align__(16) float WgT[EE][DD];   // 8 KB
    __shared__ ushort coreS[RPB * CS_S];          // 17.4 KB
    __shared__ int    le[2 * RPB];                // e0 at [s], e1 at [RPB+s]
    __shared__ float  lw[2 * RPB];
    __shared__ float  wES[RPB];
    __shared__ float  redS[4][RPB];               // 1 KB
    __shared__ float  mvS[EE], boS[EE];

    const int t = threadIdx.x;
    const int rowBase = blockIdx.x * RPB;
    const int lane = t & 63;
    const int wid  = t >> 6;          // 0..15
    const int m16  = lane & 15;
    const int q    = lane >> 4;       // 0..3
    const int rg   = wid >> 2;        // row-group: rows rg*16 .. +16
    const int cq   = wid & 3;         // col-quarter: cols cq*32 .. +32

    // ---- stage WgT (first 256 threads, verified pattern) + consts ----
    if (t < 256){
        const float4* g = (const float4*)(Wg + t * EE);
        const float4 a = g[0], b = g[1];
        WgT[0][t] = a.x; WgT[1][t] = a.y; WgT[2][t] = a.z; WgT[3][t] = a.w;
        WgT[4][t] = b.x; WgT[5][t] = b.y; WgT[6][t] = b.z; WgT[7][t] = b.w;
    }
    if (t < EE){ mvS[t] = 1.0f / (1.0f + __expf(-mix_logit[t])); boS[t] = bo[t]; }

    // ---- A fragments into registers: row rg*16+m16, chunk (ks, q) ----
    // Same RNE f2bf as the verified staged path -> bit-identical operands.
    short8 af[8];
    {
        const float* xr = x + (size_t)(rowBase + rg * 16 + m16) * DD;
        #pragma unroll
        for (int ks = 0; ks < 8; ks++){
            const float4 v0 = *(const float4*)(xr + ks * 32 + q * 8);
            const float4 v1 = *(const float4*)(xr + ks * 32 + q * 8 + 4);
            short8 o;
            o[0] = (short)f2bf(v0.x); o[1] = (short)f2bf(v0.y);
            o[2] = (short)f2bf(v0.z); o[3] = (short)f2bf(v0.w);
            o[4] = (short)f2bf(v1.x); o[5] = (short)f2bf(v1.y);
            o[6] = (short)f2bf(v1.z); o[7] = (short)f2bf(v1.w);
            af[ks] = o;
        }
    }
    __syncthreads();   // WgT visible before routing reads it

    // ---- routing: 16 waves x 4 rows, per-row math bit-identical ----
    for (int it = 0; it < 4; it++){
        const int slot = wid * 4 + it;             // 0..63
        const int row  = rowBase + slot;
        const float4 xv = *(const float4*)(x + (size_t)row * DD + lane * 4);
        float p[EE];
        #pragma unroll
        for (int e = 0; e < EE; e++){
            const float4 ww = *(const float4*)&WgT[e][lane * 4];
            p[e] = xv.x * ww.x + xv.y * ww.y + xv.z * ww.z + xv.w * ww.w;
        }
        #pragma unroll
        for (int off = 32; off >= 1; off >>= 1){
            #pragma unroll
            for (int e = 0; e < EE; e++) p[e] += __shfl_down(p[e], off, 64);
        }
        if (lane == 0){
            int e0 = 0; float l0 = p[0];
            #pragma unroll
            for (int e = 1; e < EE; e++){ if (p[e] > l0){ l0 = p[e]; e0 = e; } }
            int e1 = -1; float l1 = -3.0e38f;
            #pragma unroll
            for (int e = 0; e < EE; e++){ if (e != e0 && p[e] > l1){ l1 = p[e]; e1 = e; } }
            const float tt  = __expf(l1 - l0);            // <= 1
            const float inv = 1.0f / (1.0f + tt);
            le[slot]       = e0;  lw[slot]       = inv;
            le[RPB + slot] = e1;  lw[RPB + slot] = tt * inv;
        }
    }
    __syncthreads();

    // ---- dense expert loop ----
    const int c0 = cq * 32;
    float red[4] = {0.0f, 0.0f, 0.0f, 0.0f};      // rows rg*16 + q*4 + j

    #pragma unroll 1
    for (int e = 0; e < EE; e++){
        // per-row weight for this expert (0 if not in the row's top-2);
        // end-of-iteration barrier orders this vs prior epilogue reads
        if (t < RPB)
            wES[t] = (le[t] == e) ? lw[t] : ((le[RPB + t] == e) ? lw[RPB + t] : 0.0f);

        // ---- GEMM1: core_pre = X @ W1[e] + b1[e] (16 rows x 32 cols/wave) ----
        f32x4 acc[2];
        #pragma unroll
        for (int ct = 0; ct < 2; ct++){
            const float bj = b1[e * HH + c0 + ct * 16 + m16];
            acc[ct] = (f32x4){bj, bj, bj, bj};
        }
        const ushort* W1te = W1t + (size_t)e * HH * DD;
        #pragma unroll
        for (int ks = 0; ks < 8; ks++){
            #pragma unroll
            for (int ct = 0; ct < 2; ct++){
                const short8 bfr = *(const short8*)&W1te[(size_t)(c0 + ct * 16 + m16) * DD + ks * 32 + q * 8];
                acc[ct] = __builtin_amdgcn_mfma_f32_16x16x32_bf16(af[ks], bfr, acc[ct], 0, 0, 0);
            }
        }
        // relu -> bf16 core into shared coreS (C layout: col=m16, row=q*4+j)
        #pragma unroll
        for (int ct = 0; ct < 2; ct++)
            #pragma unroll
            for (int j = 0; j < 4; j++)
                coreS[(rg * 16 + q * 4 + j) * CS_S + c0 + ct * 16 + m16] =
                    f2bf(fmaxf(acc[ct][j], 0.0f));
        __syncthreads();   // coreS + wES visible to all waves

        // ---- GEMM2: plast_pre = core @ Wp[e] + bp[e] ----
        f32x4 acc2[2];
        #pragma unroll
        for (int ct = 0; ct < 2; ct++){
            const float bj = bp[e * HH + c0 + ct * 16 + m16];
            acc2[ct] = (f32x4){bj, bj, bj, bj};
        }
        const ushort* Wpte = Wpt + (size_t)e * HH * HH;
        #pragma unroll
        for (int ks = 0; ks < 4; ks++){
            const short8 af2 = *(const short8*)&coreS[(rg * 16 + m16) * CS_S + ks * 32 + q * 8];
            #pragma unroll
            for (int ct = 0; ct < 2; ct++){
                const short8 bfr = *(const short8*)&Wpte[(size_t)(c0 + ct * 16 + m16) * HH + ks * 32 + q * 8];
                acc2[ct] = __builtin_amdgcn_mfma_f32_16x16x32_bf16(af2, bfr, acc2[ct], 0, 0, 0);
            }
        }

        // ---- epilogue partial: red += w_row * (2-col contribution [+ bo once]) ----
        const float mv   = mvS[e];
        const float om   = 1.0f - mv;
        const float badd = (cq == 0 && m16 == 0) ? boS[e] : 0.0f;  // once per row
        float wo2[2];
        #pragma unroll
        for (int ct = 0; ct < 2; ct++) wo2[ct] = Wo[e * HH + c0 + ct * 16 + m16];

        #pragma unroll
        for (int j = 0; j < 4; j++){
            const int row = rg * 16 + q * 4 + j;   // block-local row
            float s = 0.0f;
            #pragma unroll
            for (int ct = 0; ct < 2; ct++){
                const float pl = fast_tanh(acc2[ct][j]);
                const float cv = bf2f(coreS[row * CS_S + c0 + ct * 16 + m16]);
                s = fmaf(om * cv + mv * pl, wo2[ct], s);
            }
            red[j] = fmaf(wES[row], s + badd, red[j]);
        }
        __syncthreads();   // coreS/wES consumed; next e may overwrite
    }

    // ---- final: reduce over m16 (16 col lanes), cross-cq sum, store ----
    #pragma unroll
    for (int off = 8; off >= 1; off >>= 1)
        #pragma unroll
        for (int j = 0; j < 4; j++)
            red[j] += __shfl_xor(red[j], off, 64);

    if (m16 == 0)
        #pragma unroll
        for (int j = 0; j < 4; j++)
            redS[cq][rg * 16 + q * 4 + j] = red[j];
    __syncthreads();

    if (t < RPB){
        out[rowBase + t] = redS[0][t] + redS[1][t] + redS[2][t] + redS[3][t];
    }
}

// ---------------------------------------------------------------------------
extern "C" void kernel_launch(void* const* d_in, const int* in_sizes, int n_in,
                              void* d_out, int out_size, void* d_ws, size_t ws_size,
                              hipStream_t stream) {
    (void)in_sizes; (void)n_in; (void)out_size; (void)ws_size;
    const float* x   = (const float*)d_in[0];
    const float* Wg  = (const float*)d_in[1];
    const float* W1  = (const float*)d_in[2];
    const float* b1  = (const float*)d_in[3];
    const float* Wp  = (const float*)d_in[4];
    const float* bp  = (const float*)d_in[5];
    const float* ml  = (const float*)d_in[6];
    const float* Wo  = (const float*)d_in[7];
    const float* bo  = (const float*)d_in[8];
    float* out = (float*)d_out;

    // ws layout: W1t E*H*D*2 = 512 KB | Wpt E*H*H*2 = 256 KB. Nothing else.
    char*   ws  = (char*)d_ws;
    ushort* W1t = (ushort*)ws;
    ushort* Wpt = W1t + (size_t)EE * HH * DD;

    // 2 dispatches, no memsets, no atomics, no gather.
    prep_kernel<<<TBLK, 256, 0, stream>>>(W1, Wp, W1t, Wpt);
    dense_kernel<<<BB / RPB, 1024, 0, stream>>>(
        x, Wg, W1t, b1, Wpt, bp, ml, Wo, bo, out);
}